// Round 2
// baseline (184.876 us; speedup 1.0000x reference)
//
#include <hip/hip_runtime.h>

#define IN_CH 256
#define IMG_H 56
#define IMG_W 56
#define BAND_ROWS 28             // each block computes a 28-row band of a channel pair
#define LDS_W 60                 // row stride in floats: 240B -> 16B-aligned rows
#define LDS_H 30                 // 28 interior rows + top/bottom halo
#define CH_ELEMS (LDS_W * LDS_H) // 1800 floats per channel

// out[b,c]   = conv3x3(x[b,c], w[2c])     + conv3x3(x[b,c^4], w[2(c^4)+1])
// out[b,c^4] = conv3x3(x[b,c^4], w[2(c^4)]) + conv3x3(x[b,c],  w[2c+1])
// One block per (pair p, batch b, band z); pair p -> channels c0 (bit2==0), c1=c0^4.
// LDS 14.4 KB/block (was 27.8): occupancy cap moves from LDS(5 blk/CU) to wave
// ceiling (8 blk/CU) -> more desynchronized load streams in flight per CU.
__global__ __launch_bounds__(256, 6) void dwconv_butterfly(
    const float* __restrict__ x, const float* __restrict__ wgt,
    float* __restrict__ out)
{
    __shared__ float lds[2 * CH_ELEMS];   // 14400 B

    const int tid  = threadIdx.x;
    const int p    = blockIdx.x;          // 0..127
    const int b    = blockIdx.y;          // 0..31
    const int band = blockIdx.z;          // 0..1
    const int c0   = ((p >> 2) << 3) | (p & 3);  // bit2 == 0
    const int c1   = c0 ^ 4;

    const size_t chan = (size_t)IMG_H * IMG_W;
    const float* x0 = x + ((size_t)b * IN_CH + c0) * chan;
    const float* x1 = x + ((size_t)b * IN_CH + c1) * chan;
    float* o0 = out + ((size_t)b * IN_CH + c0) * chan + (size_t)band * BAND_ROWS * IMG_W;
    float* o1 = out + ((size_t)b * IN_CH + c1) * chan + (size_t)band * BAND_ROWS * IMG_W;

    // Real input rows for this band: 29 rows.
    //   band0: global rows 0..28  -> lds rows 1..29 (lds row 0 is zero halo)
    //   band1: global rows 27..55 -> lds rows 0..28 (lds row 29 is zero halo)
    const int gbase  = band ? 27 : 0;
    const int lrbase = band ? 0 : 1;

    // ---- Phase 1a: issue all global loads (independent -> full MLP) ----
    // 2 ch * 29 rows * 14 float4 = 812 chunks. 3/thread + tail for tid<44.
    float4 v[3];
    int    ofs[3];
#pragma unroll
    for (int k = 0; k < 3; ++k) {
        const int q    = tid + 256 * k;          // < 768
        const int ch   = (q >= 406) ? 1 : 0;
        const int rem  = q - ch * 406;
        const int row  = rem / 14;               // 0..28
        const int colq = rem - row * 14;
        const float* src = (ch ? x1 : x0) + (gbase + row) * IMG_W + colq * 4;
        v[k]   = *(const float4*)src;            // 16B aligned
        ofs[k] = ch * CH_ELEMS + (lrbase + row) * LDS_W + colq * 4 + 1;
    }
    float4 v3; int ofs3 = 0; const bool has3 = (tid < 44);
    if (has3) {
        const int q    = 768 + tid;              // 768..811, all ch==1
        const int rem  = q - 406;                // 362..405
        const int row  = rem / 14;               // 25..28
        const int colq = rem - row * 14;
        v3   = *(const float4*)(x1 + (gbase + row) * IMG_W + colq * 4);
        ofs3 = CH_ELEMS + (lrbase + row) * LDS_W + colq * 4 + 1;
    }

    // ---- Phase 1b: zero halo cells (disjoint from interior loads) ----
    // Per channel: the one zero row (58 cells incl. corners) + side cols {0,57}
    // for all 30 rows (60 cells). 118/ch, 236 total (overlap at corners writes 0 twice).
    if (tid < 236) {
        const int ch = tid / 118;
        const int r  = tid - ch * 118;
        int row, col;
        if (r < 58) { row = band ? (LDS_H - 1) : 0; col = r; }
        else        { const int rr = r - 58; row = rr >> 1; col = (rr & 1) ? (LDS_W - 3) : 0; }
        lds[ch * CH_ELEMS + row * LDS_W + col] = 0.f;
    }

    // ---- Phase 1c: commit loaded values to LDS interior ----
#pragma unroll
    for (int k = 0; k < 3; ++k) {
        float* d = &lds[ofs[k]];
        d[0] = v[k].x; d[1] = v[k].y; d[2] = v[k].z; d[3] = v[k].w;
    }
    if (has3) {
        float* d = &lds[ofs3];
        d[0] = v3.x; d[1] = v3.y; d[2] = v3.z; d[3] = v3.w;
    }

    __syncthreads();

    // ---- Phase 2: weights (wave-uniform -> scalar loads) ----
    float wa[9], wb[9], wc[9], wd[9];
    {
        const float* pa = wgt + (size_t)(2 * c0) * 9;
        const float* pb = wgt + (size_t)(2 * c1 + 1) * 9;
        const float* pc = wgt + (size_t)(2 * c1) * 9;
        const float* pd = wgt + (size_t)(2 * c0 + 1) * 9;
#pragma unroll
        for (int i = 0; i < 9; ++i) {
            wa[i] = pa[i]; wb[i] = pb[i]; wc[i] = pc[i]; wd[i] = pd[i];
        }
    }

    // ---- Phase 3: compute from LDS ----
    // Output local row h (0..27) needs lds rows h..h+2 (both bands, by construction).
    auto compute_quad = [&](int idx) {
        const int h  = idx / 14;
        const int w0 = (idx - h * 14) * 4;
        float acc0[4] = {0.f, 0.f, 0.f, 0.f};
        float acc1[4] = {0.f, 0.f, 0.f, 0.f};
#pragma unroll
        for (int kh = 0; kh < 3; ++kh) {
            // lds col c holds x col c-1; need x cols w0-1..w0+4 -> lds cols w0..w0+5
            const float* p0 = &lds[(h + kh) * LDS_W + w0];             // 16B aligned
            const float* p1 = p0 + CH_ELEMS;
            const float4 a0 = *(const float4*)p0;
            const float2 b0 = *(const float2*)(p0 + 4);
            const float4 a1 = *(const float4*)p1;
            const float2 b1 = *(const float2*)(p1 + 4);
            const float r0[6] = {a0.x, a0.y, a0.z, a0.w, b0.x, b0.y};
            const float r1[6] = {a1.x, a1.y, a1.z, a1.w, b1.x, b1.y};
#pragma unroll
            for (int kw = 0; kw < 3; ++kw) {
                const float fa = wa[kh * 3 + kw], fb = wb[kh * 3 + kw];
                const float fc = wc[kh * 3 + kw], fd = wd[kh * 3 + kw];
#pragma unroll
                for (int i = 0; i < 4; ++i) {
                    acc0[i] += r0[i + kw] * fa + r1[i + kw] * fb;
                    acc1[i] += r1[i + kw] * fc + r0[i + kw] * fd;
                }
            }
        }
        *(float4*)(o0 + h * IMG_W + w0) = make_float4(acc0[0], acc0[1], acc0[2], acc0[3]);
        *(float4*)(o1 + h * IMG_W + w0) = make_float4(acc1[0], acc1[1], acc1[2], acc1[3]);
    };

    // 28*14 = 392 quads: 1 per thread + tail for tid<136
    compute_quad(tid);
    if (tid < 136) compute_quad(256 + tid);
}

extern "C" void kernel_launch(void* const* d_in, const int* in_sizes, int n_in,
                              void* d_out, int out_size, void* d_ws, size_t ws_size,
                              hipStream_t stream) {
    const float* x = (const float*)d_in[0];   // (32, 256, 56, 56) fp32
    const float* w = (const float*)d_in[1];   // (512, 1, 3, 3)   fp32
    float* out = (float*)d_out;               // (32, 256, 56, 56) fp32

    dim3 grid(IN_CH / 2, 32, 2);  // 128 channel-pairs x 32 batch x 2 row-bands
    dim3 block(256);
    dwconv_butterfly<<<grid, block, 0, stream>>>(x, w, out);
}